// Round 8
// baseline (377.340 us; speedup 1.0000x reference)
//
#include <hip/hip_runtime.h>
#include <hip/hip_bf16.h>

#define LOG2PI_F 1.8378770664093453f
#define LOG2E_F  1.4426950408889634f
#define LN2_F    0.6931471805599453f

// ws layout:
//   xyt  float2[128][4096] @ 0      (4 MB)   (Ez, Ez2), b contiguous
//   cnt  unsigned          @ 4 MB   grid-barrier counter.
// The harness re-poisons d_ws to 0xAA before EVERY launch, so cnt starts at
// 0xAAAAAAAA deterministically each launch; barrier target = 0xAAAAAAAA + grid.

__global__ __launch_bounds__(256) void fused_kernel(
    const float* __restrict__ z, const float* __restrict__ means,
    const float* __restrict__ log_vars, const float* __restrict__ w,
    float2* __restrict__ xyt, unsigned* __restrict__ cnt,
    float* __restrict__ out)
{
    __shared__ float cf[3][4][256];   // 12 KB  [A|B|C][d_local][k]
    __shared__ float red[256];        // 1 KB
    __shared__ float res[4][260];     // 4.1 KB

    const int t   = threadIdx.x;
    const int bid = (int)blockIdx.x;

    // ---- phase A: Ez/Ez2 over MC, 4 b per block, fully coalesced ----
    {
        const int row = t >> 6;            // 0..3  (b_local)
        const int s   = t & 63;            // float2 slot -> d = 2s, 2s+1
        const int b   = (bid << 2) + row;
        const float* zp = z + ((size_t)b << 7) + (s << 1);
        float s1x = 0.f, s2x = 0.f, s1y = 0.f, s2y = 0.f;
        #pragma unroll
        for (int mc = 0; mc < 16; ++mc) {
            float2 v = *(const float2*)(zp + (size_t)mc * 524288);
            s1x += v.x; s2x = fmaf(v.x, v.x, s2x);
            s1y += v.y; s2y = fmaf(v.y, v.y, s2y);
        }
        const int d = s << 1;
        xyt[((size_t)d << 12) + b]           = make_float2(s1x * 0.0625f, s2x * 0.0625f);
        xyt[(((size_t)d + 1) << 12) + b]     = make_float2(s1y * 0.0625f, s2y * 0.0625f);
    }

    // ---- grid barrier (device scope; bounded spin so a contract break
    //      shows as absmax error, never a hang) ----
    __threadfence();
    __syncthreads();
    if (t == 0) {
        __hip_atomic_fetch_add(cnt, 1u, __ATOMIC_ACQ_REL, __HIP_MEMORY_SCOPE_AGENT);
        const unsigned target = 0xAAAAAAAAu + (unsigned)gridDim.x;
        for (int it = 0; it < (1 << 27); ++it) {
            if (__hip_atomic_load(cnt, __ATOMIC_ACQUIRE,
                                  __HIP_MEMORY_SCOPE_AGENT) == target) break;
            __builtin_amdgcn_s_sleep(8);
        }
    }
    __syncthreads();
    __threadfence();

    if (bid >= 512) return;

    // ---- phase B: per-block coefficient build (LDS) + readlane lse ----
    const int bc = bid >> 5;              // 0..15  -> 256 b chunk
    const int d0 = (bid & 31) << 2;       // 0..124 -> 4 d
    const int b0 = bc << 8;

    // log_softmax(w) over K=256 (t = k)
    float wv = w[t];
    red[t] = wv; __syncthreads();
    for (int off = 128; off > 0; off >>= 1) {
        if (t < off) red[t] = fmaxf(red[t], red[t + off]);
        __syncthreads();
    }
    float m = red[0]; __syncthreads();
    red[t] = expf(wv - m); __syncthreads();
    for (int off = 128; off > 0; off >>= 1) {
        if (t < off) red[t] += red[t + off];
        __syncthreads();
    }
    const float logw = wv - m - logf(red[0]);

    // coefficients for k = t, d = d0..d0+3
    {
        const float4 mu = *(const float4*)&means[(t << 7) + d0];
        const float4 lv = *(const float4*)&log_vars[(t << 7) + d0];
        #define MK(J, MUC, LVC)                                                   \
        {                                                                         \
            float p = expf(-(LVC));                                               \
            cf[0][J][t] = (-0.5f * (LOG2PI_F + (LVC)) - 0.5f * p * (MUC) * (MUC)  \
                           + logw) * LOG2E_F;                                     \
            cf[1][J][t] = p * (MUC) * LOG2E_F;                                    \
            cf[2][J][t] = -0.5f * p * LOG2E_F;                                    \
        }
        MK(0, mu.x, lv.x) MK(1, mu.y, lv.y) MK(2, mu.z, lv.z) MK(3, mu.w, lv.w)
        #undef MK
    }
    __syncthreads();

    // wave w owns d = d0+w; lane l holds k in {4l..4l+3} coefficients in VGPRs
    {
        const int l  = t & 63;
        const int wvv = t >> 6;
        const int d  = __builtin_amdgcn_readfirstlane(d0 + wvv);

        const float4 cA = *(const float4*)&cf[0][wvv][l << 2];
        const float4 cB = *(const float4*)&cf[1][wvv][l << 2];
        const float4 cC = *(const float4*)&cf[2][wvv][l << 2];

        const float2* xp = xyt + ((size_t)d << 12) + b0 + l;
        float x0, x1, x2, x3, y0, y1, y2, y3;
        { float2 v = xp[0];   x0 = v.x; y0 = v.y; }
        { float2 v = xp[64];  x1 = v.x; y1 = v.y; }
        { float2 v = xp[128]; x2 = v.x; y2 = v.y; }
        { float2 v = xp[192]; x3 = v.x; y3 = v.y; }

        float a0 = 0.f, a1 = 0.f, a2 = 0.f, a3 = 0.f;

        #define RL(v) __int_as_float(__builtin_amdgcn_readlane(__float_as_int(v), k0))
        #define BODY(F)                                                          \
        {                                                                        \
            float sa = RL(cA.F), sb = RL(cB.F), sc = RL(cC.F);                   \
            a0 += __builtin_amdgcn_exp2f(fmaf(sc, y0, fmaf(sb, x0, sa)));        \
            a1 += __builtin_amdgcn_exp2f(fmaf(sc, y1, fmaf(sb, x1, sa)));        \
            a2 += __builtin_amdgcn_exp2f(fmaf(sc, y2, fmaf(sb, x2, sa)));        \
            a3 += __builtin_amdgcn_exp2f(fmaf(sc, y3, fmaf(sb, x3, sa)));        \
        }
        #pragma unroll 4
        for (int k0 = 0; k0 < 64; ++k0) {
            BODY(x) BODY(y) BODY(z) BODY(w)
        }
        #undef BODY
        #undef RL

        res[wvv][l]       = LN2_F * __builtin_amdgcn_logf(a0);
        res[wvv][l +  64] = LN2_F * __builtin_amdgcn_logf(a1);
        res[wvv][l + 128] = LN2_F * __builtin_amdgcn_logf(a2);
        res[wvv][l + 192] = LN2_F * __builtin_amdgcn_logf(a3);
    }
    __syncthreads();

    // out[b][d0..d0+3] as one float4 per b
    float4 o = make_float4(res[0][t], res[1][t], res[2][t], res[3][t]);
    *(float4*)&out[((size_t)(b0 + t) << 7) + d0] = o;
}

extern "C" void kernel_launch(void* const* d_in, const int* in_sizes, int n_in,
                              void* d_out, int out_size, void* d_ws, size_t ws_size,
                              hipStream_t stream) {
    const float* z        = (const float*)d_in[0];
    const float* means    = (const float*)d_in[1];
    const float* log_vars = (const float*)d_in[2];
    const float* w        = (const float*)d_in[3];
    float* out = (float*)d_out;

    char* ws = (char*)d_ws;
    float2*   xyt = (float2*)ws;
    unsigned* cnt = (unsigned*)(ws + (4 << 20));

    fused_kernel<<<1024, 256, 0, stream>>>(z, means, log_vars, w, xyt, cnt, out);
}

// Round 9
// 108.293 us; speedup vs baseline: 3.4844x; 3.4844x over previous
//
#include <hip/hip_runtime.h>
#include <hip/hip_bf16.h>

#define LOG2PI_F 1.8378770664093453f
#define LOG2E_F  1.4426950408889634f
#define LN2_F    0.6931471805599453f

// Single dispatch, NO cross-block communication: the (b,d) output tiling
// partitions z, so each block computes Ez/Ez2 for its own 256b x 8d tile
// directly from z into LDS. d_ws is completely unused.
__global__ __launch_bounds__(512) void mog_fused(
    const float* __restrict__ z, const float* __restrict__ means,
    const float* __restrict__ log_vars, const float* __restrict__ w,
    float* __restrict__ out)
{
    __shared__ float  cf[3][8][256];   // 24 KB  [A|B|C][d_local][k]
    __shared__ float2 xy[8][258];      // 16.1 KB (Ez,Ez2)[d_local][b_local]
    __shared__ float  res[8][264];     // 8.25 KB
    __shared__ float  red[256];        // 1 KB

    const int t   = threadIdx.x;
    const int bid = (int)blockIdx.x;
    // Swizzle: XCD r (= bid%8 round-robin heuristic) gets d-block pair
    // {2r, 2r+1} -- the two 8d-tiles sharing each 64B z-cacheline -- so the
    // 32B half-line reads dedupe in that XCD's L2.
    const int r  = bid & 7;
    const int g  = bid >> 3;                 // 0..31
    const int d0 = ((r << 1) + (g & 1)) << 3;  // 16 d-blocks x 8 d
    const int b0 = (g >> 1) << 8;              // 16 b-chunks x 256 b

    // ---- phase A: Ez/Ez2 for own tile (z read exactly once grid-wide) ----
    {
        const int bl = t >> 1;                 // 0..255
        const int dq = (t & 1) << 2;           // 0 or 4
        const float* zp = z + ((size_t)(b0 + bl) << 7) + d0 + dq;
        float4 s1 = {0.f,0.f,0.f,0.f}, s2 = {0.f,0.f,0.f,0.f};
        #pragma unroll
        for (int mc = 0; mc < 16; ++mc) {
            float4 v = *(const float4*)(zp + (size_t)mc * 524288);
            s1.x += v.x; s2.x = fmaf(v.x, v.x, s2.x);
            s1.y += v.y; s2.y = fmaf(v.y, v.y, s2.y);
            s1.z += v.z; s2.z = fmaf(v.z, v.z, s2.z);
            s1.w += v.w; s2.w = fmaf(v.w, v.w, s2.w);
        }
        xy[dq + 0][bl] = make_float2(s1.x * 0.0625f, s2.x * 0.0625f);
        xy[dq + 1][bl] = make_float2(s1.y * 0.0625f, s2.y * 0.0625f);
        xy[dq + 2][bl] = make_float2(s1.z * 0.0625f, s2.z * 0.0625f);
        xy[dq + 3][bl] = make_float2(s1.w * 0.0625f, s2.w * 0.0625f);
    }

    // ---- log_softmax(w) over K=256 (first 256 threads reduce) ----
    const int k = t & 255;
    const float wv = w[k];
    if (t < 256) red[t] = wv;
    __syncthreads();
    for (int off = 128; off > 0; off >>= 1) {
        if (t < off) red[t] = fmaxf(red[t], red[t + off]);
        __syncthreads();
    }
    const float m = red[0];
    __syncthreads();
    if (t < 256) red[t] = expf(wv - m);
    __syncthreads();
    for (int off = 128; off > 0; off >>= 1) {
        if (t < off) red[t] += red[t + off];
        __syncthreads();
    }
    const float logw = wv - m - logf(red[0]);

    // ---- coefficients: k = t&255; half 0 -> d0..d0+3, half 1 -> d0+4..7 ----
    {
        const int dh = (t >> 8) << 2;          // 0 or 4
        const float4 mu = *(const float4*)&means[(k << 7) + d0 + dh];
        const float4 lv = *(const float4*)&log_vars[(k << 7) + d0 + dh];
        #define MK(J, MUC, LVC)                                                  \
        {                                                                        \
            float p = expf(-(LVC));                                              \
            cf[0][dh + J][k] = (-0.5f * (LOG2PI_F + (LVC))                       \
                                - 0.5f * p * (MUC) * (MUC) + logw) * LOG2E_F;    \
            cf[1][dh + J][k] = p * (MUC) * LOG2E_F;                              \
            cf[2][dh + J][k] = -0.5f * p * LOG2E_F;                              \
        }
        MK(0, mu.x, lv.x) MK(1, mu.y, lv.y) MK(2, mu.z, lv.z) MK(3, mu.w, lv.w)
        #undef MK
    }
    __syncthreads();

    // ---- phase B: wave w owns d_local = w (uniform); lane l holds coefs
    //      for k in {4l..4l+3} in 12 VGPRs; readlane broadcast; 4 b per lane.
    {
        const int wv8 = t >> 6;                // 0..7, wave-uniform
        const int l   = t & 63;

        const float4 cA = *(const float4*)&cf[0][wv8][l << 2];
        const float4 cB = *(const float4*)&cf[1][wv8][l << 2];
        const float4 cC = *(const float4*)&cf[2][wv8][l << 2];

        float x0, x1, x2, x3, y0, y1, y2, y3;
        { float2 v = xy[wv8][l];       x0 = v.x; y0 = v.y; }
        { float2 v = xy[wv8][l +  64]; x1 = v.x; y1 = v.y; }
        { float2 v = xy[wv8][l + 128]; x2 = v.x; y2 = v.y; }
        { float2 v = xy[wv8][l + 192]; x3 = v.x; y3 = v.y; }

        float a0 = 0.f, a1 = 0.f, a2 = 0.f, a3 = 0.f;

        #define RL(v) __int_as_float(__builtin_amdgcn_readlane(__float_as_int(v), k0))
        #define BODY(F)                                                          \
        {                                                                        \
            float sa = RL(cA.F), sb = RL(cB.F), sc = RL(cC.F);                   \
            a0 += __builtin_amdgcn_exp2f(fmaf(sc, y0, fmaf(sb, x0, sa)));        \
            a1 += __builtin_amdgcn_exp2f(fmaf(sc, y1, fmaf(sb, x1, sa)));        \
            a2 += __builtin_amdgcn_exp2f(fmaf(sc, y2, fmaf(sb, x2, sa)));        \
            a3 += __builtin_amdgcn_exp2f(fmaf(sc, y3, fmaf(sb, x3, sa)));        \
        }
        #pragma unroll 4
        for (int k0 = 0; k0 < 64; ++k0) {
            BODY(x) BODY(y) BODY(z) BODY(w)
        }
        #undef BODY
        #undef RL

        res[wv8][l]       = LN2_F * __builtin_amdgcn_logf(a0);
        res[wv8][l +  64] = LN2_F * __builtin_amdgcn_logf(a1);
        res[wv8][l + 128] = LN2_F * __builtin_amdgcn_logf(a2);
        res[wv8][l + 192] = LN2_F * __builtin_amdgcn_logf(a3);
    }
    __syncthreads();

    // ---- writeout: thread t -> (b = t>>1, 4 d), 16B stores; the paired
    //      d-block on the same XCD supplies the other half of each line ----
    {
        const int bl = t >> 1;
        const int dh = (t & 1) << 2;
        float4 o = make_float4(res[dh + 0][bl], res[dh + 1][bl],
                               res[dh + 2][bl], res[dh + 3][bl]);
        *(float4*)&out[((size_t)(b0 + bl) << 7) + d0 + dh] = o;
    }
}

extern "C" void kernel_launch(void* const* d_in, const int* in_sizes, int n_in,
                              void* d_out, int out_size, void* d_ws, size_t ws_size,
                              hipStream_t stream) {
    const float* z        = (const float*)d_in[0];
    const float* means    = (const float*)d_in[1];
    const float* log_vars = (const float*)d_in[2];
    const float* w        = (const float*)d_in[3];
    float* out = (float*)d_out;

    mog_fused<<<256, 512, 0, stream>>>(z, means, log_vars, w, out);
}

// Round 10
// 106.992 us; speedup vs baseline: 3.5268x; 1.0122x over previous
//
#include <hip/hip_runtime.h>
#include <hip/hip_bf16.h>

#define LOG2PI_F 1.8378770664093453f
#define LOG2E_F  1.4426950408889634f
#define LN2_F    0.6931471805599453f

// Single dispatch, no cross-block communication. 512 blocks x 512 threads.
// Block tile: 4 d x 256 b. 8 waves = (d_local 0..3) x (k_half 0..1).
// d_ws unused.
__global__ __launch_bounds__(512, 4) void mog_fused(
    const float* __restrict__ z, const float* __restrict__ means,
    const float* __restrict__ log_vars, const float* __restrict__ w,
    float* __restrict__ out)
{
    __shared__ float  cf[3][4][256];    // 12 KB  [A|B|C][d_local][k]
    __shared__ float2 xy[4][260];       // 8.3 KB (Ez,Ez2)[d_local][b_local]
    __shared__ float  part[2][4][256];  // 8 KB   [k_half][d_local][b_local]
    __shared__ float  res[4][260];      // 4.1 KB

    const int t   = threadIdx.x;
    const int l   = t & 63;
    const int bid = (int)blockIdx.x;
    // bid = (db&3)*128 + (db>>2)*16 + bc. The 4 d-blocks sharing each 64 B
    // z-line (same bc, same db-group) all satisfy bid%8 == bc%8 -> same XCD
    // under round-robin dispatch; L3 backstops if the mapping heuristic fails.
    const int db = (bid >> 7) | (((bid >> 4) & 7) << 2);
    const int b0 = (bid & 15) << 8;
    const int d0 = db << 2;

    // ---- phase A: Ez/Ez2 (threads 0..255; 16 independent loads in flight) --
    if (t < 256) {
        const float* zp = z + ((size_t)(b0 + t) << 7) + d0;
        float4 v[16];
        #pragma unroll
        for (int mc = 0; mc < 16; ++mc)
            v[mc] = *(const float4*)(zp + (size_t)mc * 524288);
        float4 s1 = {0.f,0.f,0.f,0.f}, s2 = {0.f,0.f,0.f,0.f};
        #pragma unroll
        for (int mc = 0; mc < 16; ++mc) {
            s1.x += v[mc].x; s2.x = fmaf(v[mc].x, v[mc].x, s2.x);
            s1.y += v[mc].y; s2.y = fmaf(v[mc].y, v[mc].y, s2.y);
            s1.z += v[mc].z; s2.z = fmaf(v[mc].z, v[mc].z, s2.z);
            s1.w += v[mc].w; s2.w = fmaf(v[mc].w, v[mc].w, s2.w);
        }
        xy[0][t] = make_float2(s1.x * 0.0625f, s2.x * 0.0625f);
        xy[1][t] = make_float2(s1.y * 0.0625f, s2.y * 0.0625f);
        xy[2][t] = make_float2(s1.z * 0.0625f, s2.z * 0.0625f);
        xy[3][t] = make_float2(s1.w * 0.0625f, s2.w * 0.0625f);
    }

    // ---- log_softmax(w): per-wave shuffle reduce, barrier-free ----
    float lse_w;
    {
        const float4 w4 = *(const float4*)&w[l << 2];
        float mx = fmaxf(fmaxf(w4.x, w4.y), fmaxf(w4.z, w4.w));
        #pragma unroll
        for (int s = 32; s; s >>= 1) mx = fmaxf(mx, __shfl_xor(mx, s, 64));
        float es = expf(w4.x - mx) + expf(w4.y - mx)
                 + expf(w4.z - mx) + expf(w4.w - mx);
        #pragma unroll
        for (int s = 32; s; s >>= 1) es += __shfl_xor(es, s, 64);
        lse_w = mx + logf(es);           // wave-uniform
    }

    // ---- coefficients: thread t -> k = t&255, d-pair dh = (t>>8)*2 ----
    {
        const int kk = t & 255;
        const int dh = (t >> 8) << 1;
        const float logw = w[kk] - lse_w;
        const float2 mu  = *(const float2*)&means[(kk << 7) + d0 + dh];
        const float2 lv2 = *(const float2*)&log_vars[(kk << 7) + d0 + dh];
        {
            float p = expf(-lv2.x);
            cf[0][dh][kk] = (-0.5f * (LOG2PI_F + lv2.x)
                             - 0.5f * p * mu.x * mu.x + logw) * LOG2E_F;
            cf[1][dh][kk] = p * mu.x * LOG2E_F;
            cf[2][dh][kk] = -0.5f * p * LOG2E_F;
        }
        {
            float p = expf(-lv2.y);
            cf[0][dh + 1][kk] = (-0.5f * (LOG2PI_F + lv2.y)
                                 - 0.5f * p * mu.y * mu.y + logw) * LOG2E_F;
            cf[1][dh + 1][kk] = p * mu.y * LOG2E_F;
            cf[2][dh + 1][kk] = -0.5f * p * LOG2E_F;
        }
    }
    __syncthreads();

    // ---- phase B: wave = (dl, kh); lane holds 2 k's of coefs; 4 b/lane ----
    const int dl = (t >> 6) & 3;         // wave-uniform
    const int kh = t >> 8;               // wave-uniform
    {
        const int kb = (kh << 7) + (l << 1);
        const float2 cA = *(const float2*)&cf[0][dl][kb];
        const float2 cB = *(const float2*)&cf[1][dl][kb];
        const float2 cC = *(const float2*)&cf[2][dl][kb];

        float x0, x1, x2, x3, y0, y1, y2, y3;
        { float2 v = xy[dl][l];       x0 = v.x; y0 = v.y; }
        { float2 v = xy[dl][l +  64]; x1 = v.x; y1 = v.y; }
        { float2 v = xy[dl][l + 128]; x2 = v.x; y2 = v.y; }
        { float2 v = xy[dl][l + 192]; x3 = v.x; y3 = v.y; }

        float a0 = 0.f, a1 = 0.f, a2 = 0.f, a3 = 0.f;

        #define RL(v) __int_as_float(__builtin_amdgcn_readlane(__float_as_int(v), j))
        #define BODY(F)                                                         \
        {                                                                       \
            float sa = RL(cA.F), sb = RL(cB.F), sc = RL(cC.F);                  \
            a0 += __builtin_amdgcn_exp2f(fmaf(sc, y0, fmaf(sb, x0, sa)));       \
            a1 += __builtin_amdgcn_exp2f(fmaf(sc, y1, fmaf(sb, x1, sa)));       \
            a2 += __builtin_amdgcn_exp2f(fmaf(sc, y2, fmaf(sb, x2, sa)));       \
            a3 += __builtin_amdgcn_exp2f(fmaf(sc, y3, fmaf(sb, x3, sa)));       \
        }
        #pragma unroll 4
        for (int j = 0; j < 64; ++j) {    // j = source lane; 2 k per j
            BODY(x) BODY(y)
        }
        #undef BODY
        #undef RL

        part[kh][dl][l]       = a0;
        part[kh][dl][l +  64] = a1;
        part[kh][dl][l + 128] = a2;
        part[kh][dl][l + 192] = a3;
    }
    __syncthreads();

    // ---- combine k-halves + log (kh==0 waves) ----
    if (kh == 0) {
        float s0 = part[0][dl][l]       + part[1][dl][l];
        float s1 = part[0][dl][l +  64] + part[1][dl][l +  64];
        float s2 = part[0][dl][l + 128] + part[1][dl][l + 128];
        float s3 = part[0][dl][l + 192] + part[1][dl][l + 192];
        res[dl][l]       = LN2_F * __builtin_amdgcn_logf(s0);
        res[dl][l +  64] = LN2_F * __builtin_amdgcn_logf(s1);
        res[dl][l + 128] = LN2_F * __builtin_amdgcn_logf(s2);
        res[dl][l + 192] = LN2_F * __builtin_amdgcn_logf(s3);
    }
    __syncthreads();

    // ---- writeout: thread t<256 -> b = t, 16 B store ----
    if (t < 256) {
        float4 o = make_float4(res[0][t], res[1][t], res[2][t], res[3][t]);
        *(float4*)&out[((size_t)(b0 + t) << 7) + d0] = o;
    }
}

extern "C" void kernel_launch(void* const* d_in, const int* in_sizes, int n_in,
                              void* d_out, int out_size, void* d_ws, size_t ws_size,
                              hipStream_t stream) {
    const float* z        = (const float*)d_in[0];
    const float* means    = (const float*)d_in[1];
    const float* log_vars = (const float*)d_in[2];
    const float* w        = (const float*)d_in[3];
    float* out = (float*)d_out;

    mog_fused<<<512, 512, 0, stream>>>(z, means, log_vars, w, out);
}